// Round 12
// baseline (268.826 us; speedup 1.0000x reference)
//
#include <hip/hip_runtime.h>

// GeodesicShooting on [160^3,3] f32, AoS layout. Structure = R11 with BATCHED
// blur staging: fixed-trip unrolled load-batch (all global float4 loads issue
// before any ds_write) -> restores MLP that the runtime staging loop serialized.
//   z-blur: LDS slab [16][120]float4 (+pad), 4-voxel compute groups, b128 reads
//   yx-blur fused: LDS plane tile (+pad), float4 staging + b128 tap reads
//   steps: R4 MLP gather + XCD swizzle (~24 us, at traffic floor)
// Identity grid folded analytically: s = idx + 79.5*v.
// Parity: z vel->WS ; yx WS->OUT(scale) ; steps OUT->WS->...->OUT (6 steps).

constexpr int W = 160, H = 160, D = 160;
constexpr int NVOX = W * H * D;            // 4,096,000
constexpr int NSTEPS = 6;
constexpr float HSC = 79.5f;               // 0.5*(W-1)

constexpr int ZT = 8;                      // z outputs per block
constexpr int ZR = ZT + 8;                 // 16 staged z-rows
constexpr int ZSTG = ZR * 120;             // 1920 staged float4
constexpr int ZPAD = 2048;                 // padded LDS slots (8 * 256)

constexpr int YT = 8;                      // y outputs per block
constexpr int XT = 80;                     // x outputs per block (half row)
constexpr int YR = YT + 8;                 // 16 staged rows
constexpr int XRG = 22;                    // staged 4-voxel col groups (88 voxels)
constexpr int XOG = 20;                    // output 4-voxel col groups
constexpr int YXSTG = YR * XRG * 3;        // 1056 staged float4
constexpr int YXPAD = 1280;                // padded LDS slots (5 * 256)

__device__ __forceinline__ int iclamp(int v, int lo, int hi) {
    return v < lo ? lo : (v > hi ? hi : v);
}

// ---- blur along z: LDS slab, BATCHED float4 staging, 4-voxel compute ----
__global__ void blur_z_lds4(const float* __restrict__ in, float* __restrict__ out,
                            const float* __restrict__ gk)
{
    __shared__ float4 raw[ZPAD];           // 32 KB -> 5 blocks/CU

    int b = blockIdx.x;
    int bs = (b & 7) * 400 + (b >> 3);     // 3200 blocks, bijective XCD swizzle
    int y    = bs % H;
    int zseg = bs / H;                     // 0..19
    int z0 = zseg * ZT;
    int tid = threadIdx.x;

    float kw[9];
#pragma unroll
    for (int t = 0; t < 9; ++t) kw[t] = gk[t];

    // staging: 8 unrolled independent loads FIRST, then 8 select+writes
    float4 tmp[8];
    bool   oks[8];
#pragma unroll
    for (int k = 0; k < 8; ++k) {
        int j  = k * 256 + tid;
        int jc = j < ZSTG ? j : ZSTG - 1;          // clamp pad slots to a safe addr
        int row = jc / 120, col = jc % 120;
        int zz = z0 - 4 + row;
        oks[k] = (zz >= 0) && (zz < D);
        const float4* p = (const float4*)(in + ((size_t)iclamp(zz, 0, D - 1) * H + y) * 480);
        tmp[k] = p[col];
    }
    const float4 zero4 = make_float4(0.f, 0.f, 0.f, 0.f);
#pragma unroll
    for (int k = 0; k < 8; ++k) {
        raw[k * 256 + tid] = oks[k] ? tmp[k] : zero4;   // pad slots get garbage-safe data
    }
    __syncthreads();

    // compute 8 z x 40 col-groups (4 voxels each): 27 b128 LDS reads + 108 FMA
    for (int j = tid; j < ZT * 40; j += 256) {
        int xg = j % 40;
        int t  = j / 40;
        float a[12] = {0,0,0,0,0,0,0,0,0,0,0,0};
#pragma unroll
        for (int k = 0; k < 9; ++k) {
            const float4* r = &raw[(t + k) * 120 + xg * 3];
            float4 u0 = r[0], u1 = r[1], u2 = r[2];
            float w = kw[k];
            a[0]  = fmaf(w, u0.x, a[0]);  a[1]  = fmaf(w, u0.y, a[1]);
            a[2]  = fmaf(w, u0.z, a[2]);  a[3]  = fmaf(w, u0.w, a[3]);
            a[4]  = fmaf(w, u1.x, a[4]);  a[5]  = fmaf(w, u1.y, a[5]);
            a[6]  = fmaf(w, u1.z, a[6]);  a[7]  = fmaf(w, u1.w, a[7]);
            a[8]  = fmaf(w, u2.x, a[8]);  a[9]  = fmaf(w, u2.y, a[9]);
            a[10] = fmaf(w, u2.z, a[10]); a[11] = fmaf(w, u2.w, a[11]);
        }
        float4* q = (float4*)(out + ((size_t)(z0 + t) * H + y) * 480 + (size_t)xg * 12);
        q[0] = make_float4(a[0], a[1], a[2],  a[3]);
        q[1] = make_float4(a[4], a[5], a[6],  a[7]);
        q[2] = make_float4(a[8], a[9], a[10], a[11]);
    }
}

// ---- fused y-blur + x-blur (+ 2^-6 scale), BATCHED staging ----
__global__ void blur_yx_lds4(const float* __restrict__ in, float* __restrict__ out,
                             const float* __restrict__ gk, float scale)
{
    __shared__ float4 raw[YXPAD];          // 20.5 KB
    __shared__ float4 yb [YT * XRG * 3];   //  8.4 KB   -> ~29 KB total, 5 blocks/CU

    int b = blockIdx.x;
    int bs = (b & 7) * 800 + (b >> 3);     // 6400 blocks, bijective
    int xh   = bs % 2;
    int t2   = bs / 2;
    int yseg = t2 % 20;
    int z    = t2 / 20;
    int y0 = yseg * YT;
    int x0 = xh * XT;
    int tid = threadIdx.x;

    float kw[9];
#pragma unroll
    for (int t = 0; t < 9; ++t) kw[t] = gk[t];

    const size_t planeBase = (size_t)z * H * W * 3;    // floats

    // staging: 5 unrolled independent loads FIRST, then select+writes.
    // Slot j -> row=j/66, group g=(j%66)/3, part u=(j%66)%3; voxel xb=x0-4+4g.
    float4 tmp[5];
    bool   oks[5];
#pragma unroll
    for (int k = 0; k < 5; ++k) {
        int j  = k * 256 + tid;
        int jc = j < YXSTG ? j : YXSTG - 1;
        int row = jc / (XRG * 3);
        int rem = jc % (XRG * 3);
        int g = rem / 3, u = rem % 3;
        int yy = y0 - 4 + row;
        int xb = x0 - 4 + g * 4;
        oks[k] = (yy >= 0) && (yy < H) && (xb >= 0) && (xb <= W - 4);
        const float4* p = (const float4*)(in + planeBase +
            ((size_t)iclamp(yy, 0, H - 1) * W + iclamp(xb, 0, W - 4)) * 3);
        tmp[k] = p[u];
    }
    const float4 zero4 = make_float4(0.f, 0.f, 0.f, 0.f);
#pragma unroll
    for (int k = 0; k < 5; ++k) {
        raw[k * 256 + tid] = oks[k] ? tmp[k] : zero4;
    }
    __syncthreads();

    // y-blur: 8 rows x 22 groups
    for (int j = tid; j < YT * XRG; j += 256) {
        int g   = j % XRG;
        int row = j / XRG;
        float a[12] = {0,0,0,0,0,0,0,0,0,0,0,0};
#pragma unroll
        for (int k = 0; k < 9; ++k) {
            const float4* r = &raw[(row + k) * (XRG * 3) + g * 3];
            float4 u0 = r[0], u1 = r[1], u2 = r[2];
            float w = kw[k];
            a[0]  = fmaf(w, u0.x, a[0]);  a[1]  = fmaf(w, u0.y, a[1]);
            a[2]  = fmaf(w, u0.z, a[2]);  a[3]  = fmaf(w, u0.w, a[3]);
            a[4]  = fmaf(w, u1.x, a[4]);  a[5]  = fmaf(w, u1.y, a[5]);
            a[6]  = fmaf(w, u1.z, a[6]);  a[7]  = fmaf(w, u1.w, a[7]);
            a[8]  = fmaf(w, u2.x, a[8]);  a[9]  = fmaf(w, u2.y, a[9]);
            a[10] = fmaf(w, u2.z, a[10]); a[11] = fmaf(w, u2.w, a[11]);
        }
        yb[row * (XRG * 3) + g * 3 + 0] = make_float4(a[0], a[1], a[2],  a[3]);
        yb[row * (XRG * 3) + g * 3 + 1] = make_float4(a[4], a[5], a[6],  a[7]);
        yb[row * (XRG * 3) + g * 3 + 2] = make_float4(a[8], a[9], a[10], a[11]);
    }
    __syncthreads();

    // x-blur + scale: 8 rows x 20 output groups; window = 9 float4 (12 voxels)
    for (int j = tid; j < YT * XOG; j += 256) {
        int xg = j % XOG;
        int yo = j / XOG;
        float wv[36];
#pragma unroll
        for (int m = 0; m < 9; ++m) {
            float4 u = yb[yo * (XRG * 3) + xg * 3 + m];
            wv[4 * m + 0] = u.x; wv[4 * m + 1] = u.y;
            wv[4 * m + 2] = u.z; wv[4 * m + 3] = u.w;
        }
        float o[12];
#pragma unroll
        for (int jj = 0; jj < 4; ++jj) {
#pragma unroll
            for (int cth = 0; cth < 3; ++cth) {
                float s = 0.f;
#pragma unroll
                for (int t = 0; t < 9; ++t)
                    s = fmaf(kw[t], wv[3 * (jj + t) + cth], s);
                o[3 * jj + cth] = s * scale;
            }
        }
        float4* q = (float4*)(out + planeBase +
            ((size_t)(y0 + yo) * W + (x0 + xg * 4)) * 3);
        q[0] = make_float4(o[0], o[1], o[2],  o[3]);
        q[1] = make_float4(o[4], o[5], o[6],  o[7]);
        q[2] = make_float4(o[8], o[9], o[10], o[11]);
    }
}

// ---- one scaling-and-squaring step: out = v + trilerp(v, id + v), AoS ----
__global__ void step_kernel(const float* __restrict__ v, float* __restrict__ out)
{
    int b = blockIdx.x;
    int bs = (b & 7) * 2000 + (b >> 3);                 // bijective XCD swizzle
    int i = bs * blockDim.x + threadIdx.x;
    int x = i % W;
    int t = i / W;
    int y = t % H;
    int z = t / H;

    const float* pv = v + (size_t)i * 3;
    float vx = pv[0], vy = pv[1], vz = pv[2];

    float sx = fmaf(vx, HSC, (float)x);
    float sy = fmaf(vy, HSC, (float)y);
    float sz = fmaf(vz, HSC, (float)z);

    float fx = floorf(sx), fy = floorf(sy), fz = floorf(sz);
    int x0 = (int)fx, y0 = (int)fy, z0 = (int)fz;
    float wx1 = sx - fx, wy1 = sy - fy, wz1 = sz - fz;
    float wx0 = 1.f - wx1, wy0 = 1.f - wy1, wz0 = 1.f - wz1;

    wx0 *= (x0     >= 0 && x0     < W) ? 1.f : 0.f;
    wx1 *= (x0 + 1 >= 0 && x0 + 1 < W) ? 1.f : 0.f;
    wy0 *= (y0     >= 0 && y0     < H) ? 1.f : 0.f;
    wy1 *= (y0 + 1 >= 0 && y0 + 1 < H) ? 1.f : 0.f;
    wz0 *= (z0     >= 0 && z0     < D) ? 1.f : 0.f;
    wz1 *= (z0 + 1 >= 0 && z0 + 1 < D) ? 1.f : 0.f;

    int xc0 = iclamp(x0, 0, W - 1), xc1 = iclamp(x0 + 1, 0, W - 1);
    int yc0 = iclamp(y0, 0, H - 1), yc1 = iclamp(y0 + 1, 0, H - 1);
    int zc0 = iclamp(z0, 0, D - 1), zc1 = iclamp(z0 + 1, 0, D - 1);

    int idx[8];
    idx[0] = (zc0 * H + yc0) * W + xc0;
    idx[1] = (zc0 * H + yc0) * W + xc1;
    idx[2] = (zc0 * H + yc1) * W + xc0;
    idx[3] = (zc0 * H + yc1) * W + xc1;
    idx[4] = (zc1 * H + yc0) * W + xc0;
    idx[5] = (zc1 * H + yc0) * W + xc1;
    idx[6] = (zc1 * H + yc1) * W + xc0;
    idx[7] = (zc1 * H + yc1) * W + xc1;

    float c[8][3];
#pragma unroll
    for (int k = 0; k < 8; ++k) {
        const float* p = v + (size_t)idx[k] * 3;
        c[k][0] = p[0];
        c[k][1] = p[1];
        c[k][2] = p[2];
    }

    float w8[8];
    w8[0] = wz0 * wy0 * wx0;
    w8[1] = wz0 * wy0 * wx1;
    w8[2] = wz0 * wy1 * wx0;
    w8[3] = wz0 * wy1 * wx1;
    w8[4] = wz1 * wy0 * wx0;
    w8[5] = wz1 * wy0 * wx1;
    w8[6] = wz1 * wy1 * wx0;
    w8[7] = wz1 * wy1 * wx1;

    float r0 = vx, r1 = vy, r2 = vz;
#pragma unroll
    for (int k = 0; k < 8; ++k) {
        r0 = fmaf(w8[k], c[k][0], r0);
        r1 = fmaf(w8[k], c[k][1], r1);
        r2 = fmaf(w8[k], c[k][2], r2);
    }

    float* q = out + (size_t)i * 3;
    q[0] = r0;
    q[1] = r1;
    q[2] = r2;
}

extern "C" void kernel_launch(void* const* d_in, const int* in_sizes, int n_in,
                              void* d_out, int out_size, void* d_ws, size_t ws_size,
                              hipStream_t stream)
{
    const float* vel = (const float*)d_in[0];
    // d_in[1] (identity grid) folded analytically
    const float* gk  = (const float*)d_in[2];   // 9 taps

    float* OUT = (float*)d_out;
    float* WS  = (float*)d_ws;                  // one [NVOX,3] f32 buffer

    const int threads = 256;
    const int zBlocks   = H * (D / ZT);                     // 3200
    const int yxBlocks  = D * (H / YT) * (W / XT);          // 6400
    const int stepBlocks = NVOX / threads;                  // 16000
    const float scale = 1.0f / (float)(1 << NSTEPS);        // 2^-6

    // blur: vel -> WS (z), WS -> OUT (y+x fused, scaled)
    blur_z_lds4 <<<zBlocks,  threads, 0, stream>>>(vel, WS, gk);
    blur_yx_lds4<<<yxBlocks, threads, 0, stream>>>(WS, OUT, gk, scale);

    // 6 squaring steps: OUT -> WS -> OUT -> WS -> OUT -> WS -> OUT
    step_kernel<<<stepBlocks, threads, 0, stream>>>(OUT, WS);
    step_kernel<<<stepBlocks, threads, 0, stream>>>(WS, OUT);
    step_kernel<<<stepBlocks, threads, 0, stream>>>(OUT, WS);
    step_kernel<<<stepBlocks, threads, 0, stream>>>(WS, OUT);
    step_kernel<<<stepBlocks, threads, 0, stream>>>(OUT, WS);
    step_kernel<<<stepBlocks, threads, 0, stream>>>(WS, OUT);
}

// Round 13
// 227.059 us; speedup vs baseline: 1.1839x; 1.1839x over previous
//
#include <hip/hip_runtime.h>

// GeodesicShooting on [160^3,3] f32, AoS layout. Structure = R11 with staging
// via __builtin_amdgcn_global_load_lds (width=16): no VGPR round-trip (R12's
// scratch-spill bug), no per-iteration vmcnt drain (R11's serialization).
// Zero-padding moved from staged DATA to compute-time WEIGHT masks, so the DMA
// needs no select; halo slots hold clamped-address garbage multiplied by 0.
//   z-blur: LDS slab [16][120]float4, 4-voxel compute groups, b128 reads
//   yx-blur fused: LDS plane tile, b128 tap reads, 2^-6 scale fused
//   steps: R4 MLP gather + XCD swizzle (~24 us, near traffic floor)
// Identity grid folded analytically: s = idx + 79.5*v.
// Parity: z vel->WS ; yx WS->OUT(scale) ; steps OUT->WS->...->OUT (6 steps).

constexpr int W = 160, H = 160, D = 160;
constexpr int NVOX = W * H * D;            // 4,096,000
constexpr int NSTEPS = 6;
constexpr float HSC = 79.5f;               // 0.5*(W-1)

constexpr int ZT = 8;                      // z outputs per block
constexpr int ZR = ZT + 8;                 // 16 staged z-rows
constexpr int ZSTG = ZR * 120;             // 1920 staged float4
constexpr int ZPAD = 2048;                 // 8 * 256 slots

constexpr int YT = 8;                      // y outputs per block
constexpr int XT = 80;                     // x outputs per block (half row)
constexpr int YR = YT + 8;                 // 16 staged rows
constexpr int XRG = 22;                    // staged 4-voxel col groups (88 voxels)
constexpr int XOG = 20;                    // output 4-voxel col groups
constexpr int YXSTG = YR * XRG * 3;        // 1056 staged float4
constexpr int YXPAD = 1280;                // 5 * 256 slots

typedef const __attribute__((address_space(1))) void* gas_t;
typedef __attribute__((address_space(3))) void* las_t;

__device__ __forceinline__ int iclamp(int v, int lo, int hi) {
    return v < lo ? lo : (v > hi ? hi : v);
}

// ---- blur along z: global_load_lds staging, weight-masked zero padding ----
__global__ void blur_z_lds4(const float* __restrict__ in, float* __restrict__ out,
                            const float* __restrict__ gk)
{
    __shared__ float4 raw[ZPAD];           // 32 KB -> 5 blocks/CU

    int b = blockIdx.x;
    int bs = (b & 7) * 400 + (b >> 3);     // 3200 blocks, bijective XCD swizzle
    int y    = bs % H;
    int zseg = bs / H;                     // 0..19
    int z0 = zseg * ZT;
    int tid = threadIdx.x;

    float kw[9];
#pragma unroll
    for (int t = 0; t < 9; ++t) kw[t] = gk[t];

    // staging: 8 global_load_lds per thread, ALL in flight, one drain at barrier
#pragma unroll
    for (int k = 0; k < 8; ++k) {
        int j  = k * 256 + tid;
        int jc = j < ZSTG ? j : ZSTG - 1;           // pad slots load safe addr
        int row = jc / 120, col = jc % 120;
        int zz = iclamp(z0 - 4 + row, 0, D - 1);    // clamped; masked by weight
        const float* gsrc = in + ((size_t)zz * H + y) * 480 + (size_t)col * 4;
        __builtin_amdgcn_global_load_lds((gas_t)gsrc, (las_t)&raw[j], 16, 0, 0);
    }
    __syncthreads();

    // compute 8 z x 40 col-groups (4 voxels each); zero-pad via weight mask
    for (int j = tid; j < ZT * 40; j += 256) {
        int xg = j % 40;
        int t  = j / 40;
        float a[12] = {0,0,0,0,0,0,0,0,0,0,0,0};
#pragma unroll
        for (int k = 0; k < 9; ++k) {
            float w = ((unsigned)(z0 - 4 + t + k) < (unsigned)D) ? kw[k] : 0.0f;
            const float4* r = &raw[(t + k) * 120 + xg * 3];
            float4 u0 = r[0], u1 = r[1], u2 = r[2];
            a[0]  = fmaf(w, u0.x, a[0]);  a[1]  = fmaf(w, u0.y, a[1]);
            a[2]  = fmaf(w, u0.z, a[2]);  a[3]  = fmaf(w, u0.w, a[3]);
            a[4]  = fmaf(w, u1.x, a[4]);  a[5]  = fmaf(w, u1.y, a[5]);
            a[6]  = fmaf(w, u1.z, a[6]);  a[7]  = fmaf(w, u1.w, a[7]);
            a[8]  = fmaf(w, u2.x, a[8]);  a[9]  = fmaf(w, u2.y, a[9]);
            a[10] = fmaf(w, u2.z, a[10]); a[11] = fmaf(w, u2.w, a[11]);
        }
        float4* q = (float4*)(out + ((size_t)(z0 + t) * H + y) * 480 + (size_t)xg * 12);
        q[0] = make_float4(a[0], a[1], a[2],  a[3]);
        q[1] = make_float4(a[4], a[5], a[6],  a[7]);
        q[2] = make_float4(a[8], a[9], a[10], a[11]);
    }
}

// ---- fused y-blur + x-blur (+ 2^-6 scale), global_load_lds staging ----
__global__ void blur_yx_lds4(const float* __restrict__ in, float* __restrict__ out,
                             const float* __restrict__ gk, float scale)
{
    __shared__ float4 raw[YXPAD];          // 20.5 KB
    __shared__ float4 yb [YT * XRG * 3];   //  8.4 KB -> ~29 KB, 5 blocks/CU

    int b = blockIdx.x;
    int bs = (b & 7) * 800 + (b >> 3);     // 6400 blocks, bijective
    int xh   = bs % 2;
    int t2   = bs / 2;
    int yseg = t2 % 20;
    int z    = t2 / 20;
    int y0 = yseg * YT;
    int x0 = xh * XT;
    int tid = threadIdx.x;

    float kw[9];
#pragma unroll
    for (int t = 0; t < 9; ++t) kw[t] = gk[t];

    const size_t planeBase = (size_t)z * H * W * 3;    // floats

    // staging: 5 global_load_lds per thread (clamped addresses, no select)
#pragma unroll
    for (int k = 0; k < 5; ++k) {
        int j  = k * 256 + tid;
        int jc = j < YXSTG ? j : YXSTG - 1;
        int row = jc / (XRG * 3);
        int rem = jc % (XRG * 3);
        int g = rem / 3, u = rem % 3;
        int yy = iclamp(y0 - 4 + row, 0, H - 1);
        int xb = iclamp(x0 - 4 + g * 4, 0, W - 4);
        const float* gsrc = in + planeBase + ((size_t)yy * W + xb) * 3 + (size_t)u * 4;
        __builtin_amdgcn_global_load_lds((gas_t)gsrc, (las_t)&raw[j], 16, 0, 0);
    }
    __syncthreads();

    // y-blur: 8 rows x 22 groups; y zero-pad via weight mask
    for (int j = tid; j < YT * XRG; j += 256) {
        int g   = j % XRG;
        int row = j / XRG;
        float a[12] = {0,0,0,0,0,0,0,0,0,0,0,0};
#pragma unroll
        for (int k = 0; k < 9; ++k) {
            float w = ((unsigned)(y0 - 4 + row + k) < (unsigned)H) ? kw[k] : 0.0f;
            const float4* r = &raw[(row + k) * (XRG * 3) + g * 3];
            float4 u0 = r[0], u1 = r[1], u2 = r[2];
            a[0]  = fmaf(w, u0.x, a[0]);  a[1]  = fmaf(w, u0.y, a[1]);
            a[2]  = fmaf(w, u0.z, a[2]);  a[3]  = fmaf(w, u0.w, a[3]);
            a[4]  = fmaf(w, u1.x, a[4]);  a[5]  = fmaf(w, u1.y, a[5]);
            a[6]  = fmaf(w, u1.z, a[6]);  a[7]  = fmaf(w, u1.w, a[7]);
            a[8]  = fmaf(w, u2.x, a[8]);  a[9]  = fmaf(w, u2.y, a[9]);
            a[10] = fmaf(w, u2.z, a[10]); a[11] = fmaf(w, u2.w, a[11]);
        }
        yb[row * (XRG * 3) + g * 3 + 0] = make_float4(a[0], a[1], a[2],  a[3]);
        yb[row * (XRG * 3) + g * 3 + 1] = make_float4(a[4], a[5], a[6],  a[7]);
        yb[row * (XRG * 3) + g * 3 + 2] = make_float4(a[8], a[9], a[10], a[11]);
    }
    __syncthreads();

    // x-blur + scale: 8 rows x 20 groups; x zero-pad via weight mask
    for (int j = tid; j < YT * XOG; j += 256) {
        int xg = j % XOG;
        int yo = j / XOG;
        float wv[36];
#pragma unroll
        for (int m = 0; m < 9; ++m) {
            float4 u = yb[yo * (XRG * 3) + xg * 3 + m];
            wv[4 * m + 0] = u.x; wv[4 * m + 1] = u.y;
            wv[4 * m + 2] = u.z; wv[4 * m + 3] = u.w;
        }
        float o[12];
#pragma unroll
        for (int jj = 0; jj < 4; ++jj) {
#pragma unroll
            for (int cth = 0; cth < 3; ++cth) {
                float s = 0.f;
#pragma unroll
                for (int t = 0; t < 9; ++t) {
                    // staged voxel xg*4+jj+t  <->  global x = x0-4+xg*4+jj+t
                    float w = ((unsigned)(x0 - 4 + xg * 4 + jj + t) < (unsigned)W)
                                  ? kw[t] : 0.0f;
                    s = fmaf(w, wv[3 * (jj + t) + cth], s);
                }
                o[3 * jj + cth] = s * scale;
            }
        }
        float4* q = (float4*)(out + planeBase +
            ((size_t)(y0 + yo) * W + (x0 + xg * 4)) * 3);
        q[0] = make_float4(o[0], o[1], o[2],  o[3]);
        q[1] = make_float4(o[4], o[5], o[6],  o[7]);
        q[2] = make_float4(o[8], o[9], o[10], o[11]);
    }
}

// ---- one scaling-and-squaring step: out = v + trilerp(v, id + v), AoS ----
__global__ void step_kernel(const float* __restrict__ v, float* __restrict__ out)
{
    int b = blockIdx.x;
    int bs = (b & 7) * 2000 + (b >> 3);                 // bijective XCD swizzle
    int i = bs * blockDim.x + threadIdx.x;
    int x = i % W;
    int t = i / W;
    int y = t % H;
    int z = t / H;

    const float* pv = v + (size_t)i * 3;
    float vx = pv[0], vy = pv[1], vz = pv[2];

    float sx = fmaf(vx, HSC, (float)x);
    float sy = fmaf(vy, HSC, (float)y);
    float sz = fmaf(vz, HSC, (float)z);

    float fx = floorf(sx), fy = floorf(sy), fz = floorf(sz);
    int x0 = (int)fx, y0 = (int)fy, z0 = (int)fz;
    float wx1 = sx - fx, wy1 = sy - fy, wz1 = sz - fz;
    float wx0 = 1.f - wx1, wy0 = 1.f - wy1, wz0 = 1.f - wz1;

    wx0 *= (x0     >= 0 && x0     < W) ? 1.f : 0.f;
    wx1 *= (x0 + 1 >= 0 && x0 + 1 < W) ? 1.f : 0.f;
    wy0 *= (y0     >= 0 && y0     < H) ? 1.f : 0.f;
    wy1 *= (y0 + 1 >= 0 && y0 + 1 < H) ? 1.f : 0.f;
    wz0 *= (z0     >= 0 && z0     < D) ? 1.f : 0.f;
    wz1 *= (z0 + 1 >= 0 && z0 + 1 < D) ? 1.f : 0.f;

    int xc0 = iclamp(x0, 0, W - 1), xc1 = iclamp(x0 + 1, 0, W - 1);
    int yc0 = iclamp(y0, 0, H - 1), yc1 = iclamp(y0 + 1, 0, H - 1);
    int zc0 = iclamp(z0, 0, D - 1), zc1 = iclamp(z0 + 1, 0, D - 1);

    int idx[8];
    idx[0] = (zc0 * H + yc0) * W + xc0;
    idx[1] = (zc0 * H + yc0) * W + xc1;
    idx[2] = (zc0 * H + yc1) * W + xc0;
    idx[3] = (zc0 * H + yc1) * W + xc1;
    idx[4] = (zc1 * H + yc0) * W + xc0;
    idx[5] = (zc1 * H + yc0) * W + xc1;
    idx[6] = (zc1 * H + yc1) * W + xc0;
    idx[7] = (zc1 * H + yc1) * W + xc1;

    float c[8][3];
#pragma unroll
    for (int k = 0; k < 8; ++k) {
        const float* p = v + (size_t)idx[k] * 3;
        c[k][0] = p[0];
        c[k][1] = p[1];
        c[k][2] = p[2];
    }

    float w8[8];
    w8[0] = wz0 * wy0 * wx0;
    w8[1] = wz0 * wy0 * wx1;
    w8[2] = wz0 * wy1 * wx0;
    w8[3] = wz0 * wy1 * wx1;
    w8[4] = wz1 * wy0 * wx0;
    w8[5] = wz1 * wy0 * wx1;
    w8[6] = wz1 * wy1 * wx0;
    w8[7] = wz1 * wy1 * wx1;

    float r0 = vx, r1 = vy, r2 = vz;
#pragma unroll
    for (int k = 0; k < 8; ++k) {
        r0 = fmaf(w8[k], c[k][0], r0);
        r1 = fmaf(w8[k], c[k][1], r1);
        r2 = fmaf(w8[k], c[k][2], r2);
    }

    float* q = out + (size_t)i * 3;
    q[0] = r0;
    q[1] = r1;
    q[2] = r2;
}

extern "C" void kernel_launch(void* const* d_in, const int* in_sizes, int n_in,
                              void* d_out, int out_size, void* d_ws, size_t ws_size,
                              hipStream_t stream)
{
    const float* vel = (const float*)d_in[0];
    // d_in[1] (identity grid) folded analytically
    const float* gk  = (const float*)d_in[2];   // 9 taps

    float* OUT = (float*)d_out;
    float* WS  = (float*)d_ws;                  // one [NVOX,3] f32 buffer

    const int threads = 256;
    const int zBlocks   = H * (D / ZT);                     // 3200
    const int yxBlocks  = D * (H / YT) * (W / XT);          // 6400
    const int stepBlocks = NVOX / threads;                  // 16000
    const float scale = 1.0f / (float)(1 << NSTEPS);        // 2^-6

    // blur: vel -> WS (z), WS -> OUT (y+x fused, scaled)
    blur_z_lds4 <<<zBlocks,  threads, 0, stream>>>(vel, WS, gk);
    blur_yx_lds4<<<yxBlocks, threads, 0, stream>>>(WS, OUT, gk, scale);

    // 6 squaring steps: OUT -> WS -> OUT -> WS -> OUT -> WS -> OUT
    step_kernel<<<stepBlocks, threads, 0, stream>>>(OUT, WS);
    step_kernel<<<stepBlocks, threads, 0, stream>>>(WS, OUT);
    step_kernel<<<stepBlocks, threads, 0, stream>>>(OUT, WS);
    step_kernel<<<stepBlocks, threads, 0, stream>>>(WS, OUT);
    step_kernel<<<stepBlocks, threads, 0, stream>>>(OUT, WS);
    step_kernel<<<stepBlocks, threads, 0, stream>>>(WS, OUT);
}